// Round 2
// baseline (903.038 us; speedup 1.0000x reference)
//
#include <hip/hip_runtime.h>
#include <cmath>

// ---- constants from the reference ----
constexpr float ACT_NORM = 1.6789717f;
constexpr float PW0      = 0.20412414523193154f;   // sqrt(1/24)  (== pw1/sqrt3)
constexpr float PW1      = 0.35355339059327373f;   // sqrt(3/24)
constexpr float PWREC    = 0.05590169943749474f;   // sqrt(1/320)
constexpr float INV_SQ3  = 0.57735026918962576f;

__device__ __forceinline__ float silu_n(float x) {
  return x / (1.f + __expf(-x)) * ACT_NORM;
}

// ---------------- node embedding: node[:, :16] = mlp(x), geo = 0 ----------------
__global__ __launch_bounds__(256)
void emb_kernel(const float* __restrict__ x, const float* __restrict__ w0,
                const float* __restrict__ w1, float* __restrict__ node, int N) {
  const int lane = threadIdx.x & 63;
  const int lw   = threadIdx.x >> 6;
  const int gw   = blockIdx.x * 4 + lw;
  __shared__ float sH[4][64];
  const bool valid = gw < N;
  const int n = valid ? gw : 0;
  float acc = 0.f;
#pragma unroll
  for (int a = 0; a < 10; ++a) acc = fmaf(x[n * 10 + a], w0[a * 64 + lane], acc);
  acc *= 0.31622776601683794f;   // 1/sqrt(10)
  sH[lw][lane] = silu_n(acc);
  __syncthreads();
  if (valid) {
    if (lane < 16) {
      float o = 0.f;
#pragma unroll
      for (int k = 0; k < 64; ++k) o = fmaf(sH[lw][k], w1[k * 16 + lane], o);
      node[(size_t)n * 40 + lane] = o * 0.125f;  // 1/sqrt(64)
    } else if (lane < 40) {
      node[(size_t)n * 40 + lane] = 0.f;
    }
  }
}

// ---------------- node update (per mp step) ----------------
__global__ __launch_bounds__(256)
void upd_kernel(float* __restrict__ node, const float* __restrict__ msgs,
                const float* __restrict__ w0, const float* __restrict__ w1,
                const float* __restrict__ imp, float geo_scale, float inv_sqrt_deg, int N) {
  const int lane = threadIdx.x & 63;
  const int lw   = threadIdx.x >> 6;
  const int gw   = blockIdx.x * 4 + lw;
  __shared__ float sIn[4][32];
  __shared__ float sH[4][64];
  const bool valid = gw < N;
  const int n = valid ? gw : 0;
  const float mscale = imp[0] * inv_sqrt_deg;
  if (lane < 16)      sIn[lw][lane] = msgs[(size_t)n * 40 + lane] * mscale;
  else if (lane < 32) sIn[lw][lane] = node[(size_t)n * 40 + lane - 16];
  __syncthreads();
  float acc = 0.f;
#pragma unroll
  for (int a = 0; a < 32; ++a) acc = fmaf(sIn[lw][a], w0[a * 64 + lane], acc);
  acc *= 0.17677669529663687f;   // 1/sqrt(32)
  sH[lw][lane] = silu_n(acc);
  __syncthreads();
  if (valid) {
    if (lane < 16) {
      float o = 0.f;
#pragma unroll
      for (int k = 0; k < 64; ++k) o = fmaf(sH[lw][k], w1[k * 16 + lane], o);
      node[(size_t)n * 40 + lane] = o * 0.125f;
    } else if (lane < 40) {
      const size_t gi = (size_t)n * 40 + lane;
      node[gi] = fmaf(msgs[gi], mscale, node[gi]) * geo_scale;
    }
  }
}

// ---------------- inter-edge: distance embedding -> both hidden vectors ----------------
__global__ __launch_bounds__(256)
void inter_h_kernel(const float* __restrict__ pos, const int* __restrict__ iei,
                    const float* __restrict__ lw0, const float* __restrict__ rw0,
                    float* __restrict__ hL, float* __restrict__ hR, int EI) {
  const int lane = threadIdx.x & 63;
  const int lw   = threadIdx.x >> 6;
  const int gw   = blockIdx.x * 4 + lw;
  __shared__ float sD[4][20];
  const bool valid = gw < EI;
  const int e = valid ? gw : 0;
  const int rec = iei[e], lig = iei[EI + e];
  const float dx = pos[lig * 3]     - pos[rec * 3];
  const float dy = pos[lig * 3 + 1] - pos[rec * 3 + 1];
  const float dz = pos[lig * 3 + 2] - pos[rec * 3 + 2];
  const float d = sqrtf(dx * dx + dy * dy + dz * dz);
  if (lane < 20) {
    // diff = d*(21/5) - (lane+1); demb = C * sus(diff+1)*sus(1-diff)
    const float diff = d * 4.2f - (float)(lane + 1);
    const float t1 = diff + 1.f, t2 = 1.f - diff;
    float v = 0.f;
    if (t1 > 0.f && t2 > 0.f) {
      const float C = 1.14136f * 7.3890560989306495f * 4.4721359549995794f; // 1.14136*e^2*sqrt(20)
      v = C * __expf(-1.f / t1 - 1.f / t2);
    }
    sD[lw][lane] = v;
  }
  __syncthreads();
  float a0 = 0.f, a1 = 0.f;
#pragma unroll
  for (int b = 0; b < 20; ++b) {
    const float db = sD[lw][b];
    a0 = fmaf(db, lw0[b * 64 + lane], a0);
    a1 = fmaf(db, rw0[b * 64 + lane], a1);
  }
  a0 *= 0.22360679774997896f;  // 1/sqrt(20)
  a1 *= 0.22360679774997896f;
  if (valid) {
    hL[(size_t)e * 64 + lane] = silu_n(a0);
    hR[(size_t)e * 64 + lane] = silu_n(a1);
  }
}

// ---------------- fused edge MLP (layer2) + node x sh tensor product ----------------
// MODE 0: message pass  (h from edge_attr@w0; atomicAdd into msgs[dst])
// MODE 1: lig TP        (h precomputed in hSrc; direct store to ligE[e])
template <int MODE>
__global__ __launch_bounds__(512)
void tp_kernel(const float* __restrict__ node, const float* __restrict__ pos,
               const int* __restrict__ ei, const float* __restrict__ eattr,
               const float* __restrict__ w0, const float* __restrict__ W1,
               const float* __restrict__ hSrc, float* __restrict__ out, int E) {
  __shared__ __align__(16) float sW1[64 * 576];     // 147456 B (scaled by 1/8)
  __shared__ __align__(16) float sH[8][4][64];      //   8192 B
  __shared__ float sF[8][4][48];                    //   6144 B  -> 161792 B total
  const int tid  = threadIdx.x;
  const int lane = tid & 63;
  const int wv   = tid >> 6;

  // stage W1 once per block (fits 160KB LDS); fold the 1/sqrt(64) layer scale in
  for (int i = tid * 4; i < 64 * 576; i += 512 * 4) {
    float4 v = *(const float4*)&W1[i];
    v.x *= 0.125f; v.y *= 0.125f; v.z *= 0.125f; v.w *= 0.125f;
    *(float4*)&sW1[i] = v;
  }
  __syncthreads();

  const int nB = (E + 31) >> 5;
  for (int b = blockIdx.x; b < nB; b += (int)gridDim.x) {
    const int ebase = b * 32 + wv * 4;
    float rh[4][3];
    int outn[4];
    bool val[4];
#pragma unroll
    for (int s = 0; s < 4; ++s) {
      const int e0 = ebase + s;
      val[s] = e0 < E;
      const int e = val[s] ? e0 : 0;
      const int ia = ei[e], ib = ei[E + e];
      int nsrc;
      if (MODE == 0) { nsrc = ia; outn[s] = ib; }   // src features, scatter to dst
      else           { nsrc = ib; outn[s] = e;  }   // lig features, store per edge
      const float vx = pos[ib * 3]     - pos[ia * 3];
      const float vy = pos[ib * 3 + 1] - pos[ia * 3 + 1];
      const float vz = pos[ib * 3 + 2] - pos[ia * 3 + 2];
      const float rn = rsqrtf(vx * vx + vy * vy + vz * vz);
      rh[s][0] = vx * rn; rh[s][1] = vy * rn; rh[s][2] = vz * rn;
      if (MODE == 0) {
        float acc = 0.f;
#pragma unroll
        for (int a = 0; a < 5; ++a) acc = fmaf(eattr[(size_t)e * 5 + a], w0[a * 64 + lane], acc);
        acc *= 0.4472135954999579f;   // 1/sqrt(5)
        sH[wv][s][lane] = silu_n(acc);
      } else {
        sH[wv][s][lane] = hSrc[(size_t)e * 64 + lane];
      }
      if (lane < 16) {
        sF[wv][s][lane] = node[(size_t)nsrc * 40 + lane];           // xs
      } else if (lane < 24) {
        const int u = lane - 16;
        const float x0 = node[(size_t)nsrc * 40 + 16 + u * 3];
        const float x1 = node[(size_t)nsrc * 40 + 16 + u * 3 + 1];
        const float x2 = node[(size_t)nsrc * 40 + 16 + u * 3 + 2];
        sF[wv][s][16 + u]        = x0 * rh[s][0] + x1 * rh[s][1] + x2 * rh[s][2]; // dot(xv,r^)
        sF[wv][s][24 + u * 3]     = x0;                             // xv
        sF[wv][s][24 + u * 3 + 1] = x1;
        sF[wv][s][24 + u * 3 + 2] = x2;
      }
    }
    __syncthreads();   // also fences own-wave LDS writes before reads

    // w[m] for m = lane + 64*t, t=0..8 ; w = sH(64) . sW1(64x576)
    float wacc[4][9];
#pragma unroll
    for (int s = 0; s < 4; ++s)
#pragma unroll
      for (int t = 0; t < 9; ++t) wacc[s][t] = 0.f;

    for (int k4 = 0; k4 < 64; k4 += 4) {
      float4 h4[4];
#pragma unroll
      for (int s = 0; s < 4; ++s) h4[s] = *(const float4*)&sH[wv][s][k4];
#pragma unroll
      for (int kk = 0; kk < 4; ++kk) {
        float w1v[9];
        const float* rowp = &sW1[(k4 + kk) * 576 + lane];
#pragma unroll
        for (int t = 0; t < 9; ++t) w1v[t] = rowp[64 * t];
#pragma unroll
        for (int s = 0; s < 4; ++s) {
          const float hv = (&h4[s].x)[kk];
#pragma unroll
          for (int t = 0; t < 9; ++t) wacc[s][t] = fmaf(hv, w1v[t], wacc[s][t]);
        }
      }
    }

    // TP epilogue. Slots t=0..5 are scalar-path (m<384, out col = lane&15, U=(lane>>4)+4t),
    // slots 6..8 are vector-path (out col = lane&7, U=(lane>>3)+8(t-6)).
    const int ub  = lane >> 4;
    const int ub2 = lane >> 3;
#pragma unroll
    for (int s = 0; s < 4; ++s) {
      float cs = 0.f;
#pragma unroll
      for (int t = 0; t < 6; ++t)
        cs = fmaf(PW0 * sF[wv][s][ub + 4 * t], wacc[s][t], cs);   // sF[U]: xs (U<16) / dotp (U>=16)
      cs += __shfl_xor(cs, 16);
      cs += __shfl_xor(cs, 32);

      const float xsA = sF[wv][s][ub2];        // t=6: U=ub2     (<16) -> xs path
      const float xsB = sF[wv][s][ub2 + 8];    // t=7: U=ub2+8   (<16) -> xs path
      const float sxw = PW1 * (xsA * wacc[s][6] + xsB * wacc[s][7]);
      float cv0 = fmaf(PW0 * sF[wv][s][24 + ub2 * 3],     wacc[s][8], sxw * rh[s][0]); // t=8: xv path
      float cv1 = fmaf(PW0 * sF[wv][s][24 + ub2 * 3 + 1], wacc[s][8], sxw * rh[s][1]);
      float cv2 = fmaf(PW0 * sF[wv][s][24 + ub2 * 3 + 2], wacc[s][8], sxw * rh[s][2]);
      cv0 += __shfl_xor(cv0, 8); cv0 += __shfl_xor(cv0, 16); cv0 += __shfl_xor(cv0, 32);
      cv1 += __shfl_xor(cv1, 8); cv1 += __shfl_xor(cv1, 16); cv1 += __shfl_xor(cv1, 32);
      cv2 += __shfl_xor(cv2, 8); cv2 += __shfl_xor(cv2, 16); cv2 += __shfl_xor(cv2, 32);

      if (val[s]) {
        const size_t ob = (size_t)outn[s] * 40;
        if (MODE == 0) {
          if (lane < 16) atomicAdd(&out[ob + lane], cs);
          if (lane < 8) {
            atomicAdd(&out[ob + 16 + lane * 3],     cv0);
            atomicAdd(&out[ob + 16 + lane * 3 + 1], cv1);
            atomicAdd(&out[ob + 16 + lane * 3 + 2], cv2);
          }
        } else {
          if (lane < 16) out[ob + lane] = cs;
          if (lane < 8) {
            out[ob + 16 + lane * 3]     = cv0;
            out[ob + 16 + lane * 3 + 1] = cv1;
            out[ob + 16 + lane * 3 + 2] = cv2;
          }
        }
      }
    }
  }
}

// ---------------- rec MLP (layer2, 64x2560) + node x node -> 8x0e TP ----------------
__global__ __launch_bounds__(512)
void rec_kernel(const float* __restrict__ node, const float* __restrict__ ligE,
                const int* __restrict__ iei, const float* __restrict__ RW1,
                const float* __restrict__ hR, float* __restrict__ out, int EI) {
  __shared__ __align__(16) float sW1[64 * 512];    // 131072 B (one N-chunk, scaled 1/8)
  __shared__ __align__(16) float sH[8][4][64];     //   8192 B
  __shared__ float sF[8][4][80];                   //  10240 B -> 149504 B total
  const int tid  = threadIdx.x;
  const int lane = tid & 63;
  const int wv   = tid >> 6;
  const int nB = (EI + 31) >> 5;
  for (int b = blockIdx.x; b < nB; b += (int)gridDim.x) {
    const int ebase = b * 32 + wv * 4;
    bool val[4]; int eidx[4];
#pragma unroll
    for (int s = 0; s < 4; ++s) {
      const int e0 = ebase + s;
      val[s] = e0 < EI;
      const int e = val[s] ? e0 : 0;
      eidx[s] = e;
      const int rec = iei[e];
      sH[wv][s][lane] = hR[(size_t)e * 64 + lane];
      if (lane < 40) {
        sF[wv][s][lane]      = ligE[(size_t)e * 40 + lane];        // xs_l[0:16], xv_l[16:40]
        sF[wv][s][40 + lane] = node[(size_t)rec * 40 + lane];      // ys_r[40:56], yv_r[56:80]
      }
    }
    float oacc[4] = {0.f, 0.f, 0.f, 0.f};
#pragma unroll 1
    for (int nc = 0; nc < 5; ++nc) {
      __syncthreads();
      for (int i = tid * 4; i < 64 * 512; i += 512 * 4) {
        const int k = i >> 9, c = i & 511;
        float4 v = *(const float4*)&RW1[(size_t)k * 2560 + nc * 512 + c];
        v.x *= 0.125f; v.y *= 0.125f; v.z *= 0.125f; v.w *= 0.125f;
        *(float4*)&sW1[i] = v;
      }
      __syncthreads();

      float wacc[4][8];
#pragma unroll
      for (int s = 0; s < 4; ++s)
#pragma unroll
        for (int t = 0; t < 8; ++t) wacc[s][t] = 0.f;

      for (int k4 = 0; k4 < 64; k4 += 4) {
        float4 h4[4];
#pragma unroll
        for (int s = 0; s < 4; ++s) h4[s] = *(const float4*)&sH[wv][s][k4];
#pragma unroll
        for (int kk = 0; kk < 4; ++kk) {
          float w1v[8];
          const float* rowp = &sW1[(k4 + kk) * 512 + lane];
#pragma unroll
          for (int t = 0; t < 8; ++t) w1v[t] = rowp[64 * t];
#pragma unroll
          for (int s = 0; s < 4; ++s) {
            const float hv = (&h4[s].x)[kk];
#pragma unroll
            for (int t = 0; t < 8; ++t) wacc[s][t] = fmaf(hv, w1v[t], wacc[s][t]);
          }
        }
      }

      // epilogue: m = nc*512 + lane + 64t ; out col = lane&7 (uniform per lane)
      const int l3 = lane >> 3;
      if (nc < 4) {           // scalar path: uv = m>>3 in [0,256)
#pragma unroll
        for (int s = 0; s < 4; ++s) {
          float o = 0.f;
#pragma unroll
          for (int t = 0; t < 8; ++t) {
            const int uv = nc * 64 + 8 * t + l3;
            const int u = uv >> 4, v = uv & 15;
            o = fmaf(sF[wv][s][u] * sF[wv][s][40 + v], wacc[s][t], o);
          }
          oacc[s] += o;
        }
      } else {                // vector path: uv2 = (m-2048)>>3 -> u=t, v=l3
#pragma unroll
        for (int s = 0; s < 4; ++s) {
          float o = 0.f;
#pragma unroll
          for (int t = 0; t < 8; ++t) {
            const float dp = sF[wv][s][16 + t * 3]     * sF[wv][s][56 + l3 * 3]
                           + sF[wv][s][16 + t * 3 + 1] * sF[wv][s][56 + l3 * 3 + 1]
                           + sF[wv][s][16 + t * 3 + 2] * sF[wv][s][56 + l3 * 3 + 2];
            o = fmaf(dp * INV_SQ3, wacc[s][t], o);
          }
          oacc[s] += o;
        }
      }
    }
#pragma unroll
    for (int s = 0; s < 4; ++s) {
      float v = oacc[s];
      v += __shfl_xor(v, 8); v += __shfl_xor(v, 16); v += __shfl_xor(v, 32);
      if (val[s] && lane < 8) out[(size_t)eidx[s] * 8 + lane] = v * PWREC;
    }
  }
}

extern "C" void kernel_launch(void* const* d_in, const int* in_sizes, int n_in,
                              void* d_out, int out_size, void* d_ws, size_t ws_size,
                              hipStream_t stream) {
  (void)n_in; (void)out_size; (void)ws_size;
  const float* x      = (const float*)d_in[0];
  const float* pos    = (const float*)d_in[1];
  const int*   ei     = (const int*)  d_in[2];
  const float* eattr  = (const float*)d_in[3];
  const int*   iei    = (const int*)  d_in[4];
  const float* emb_w0 = (const float*)d_in[5];
  const float* emb_w1 = (const float*)d_in[6];
  const float* imp0   = (const float*)d_in[7];
  const float* m0w0   = (const float*)d_in[8];
  const float* m0w1   = (const float*)d_in[9];
  const float* u0w0   = (const float*)d_in[10];
  const float* u0w1   = (const float*)d_in[11];
  const float* imp1   = (const float*)d_in[12];
  const float* m1w0   = (const float*)d_in[13];
  const float* m1w1   = (const float*)d_in[14];
  const float* u1w0   = (const float*)d_in[15];
  const float* u1w1   = (const float*)d_in[16];
  const float* lw0    = (const float*)d_in[17];
  const float* lw1    = (const float*)d_in[18];
  const float* rw0    = (const float*)d_in[19];
  const float* rw1    = (const float*)d_in[20];

  const int N  = in_sizes[1] / 3;
  const int E  = in_sizes[2] / 2;
  const int EI = in_sizes[4] / 2;

  float* node = (float*)d_ws;
  float* msgs = node + (size_t)N * 40;
  float* hL   = msgs + (size_t)N * 40;
  float* hR   = hL + (size_t)EI * 64;
  float* ligE = hR + (size_t)EI * 64;
  float* outp = (float*)d_out;

  const float inv_sqrt_deg = 1.0f / sqrtf((float)E / (float)N);

  const int nodeBlocks = (N + 3) / 4;
  const int interBlocks = (EI + 3) / 4;

  emb_kernel<<<nodeBlocks, 256, 0, stream>>>(x, emb_w0, emb_w1, node, N);

  // message pass 0
  hipMemsetAsync(msgs, 0, (size_t)N * 40 * sizeof(float), stream);
  tp_kernel<0><<<256, 512, 0, stream>>>(node, pos, ei, eattr, m0w0, m0w1, nullptr, msgs, E);
  upd_kernel<<<nodeBlocks, 256, 0, stream>>>(node, msgs, u0w0, u0w1, imp0, 1.0f, inv_sqrt_deg, N);

  // message pass 1
  hipMemsetAsync(msgs, 0, (size_t)N * 40 * sizeof(float), stream);
  tp_kernel<0><<<256, 512, 0, stream>>>(node, pos, ei, eattr, m1w0, m1w1, nullptr, msgs, E);
  upd_kernel<<<nodeBlocks, 256, 0, stream>>>(node, msgs, u1w0, u1w1, imp1, 0.5f, inv_sqrt_deg, N);

  // inter edges
  inter_h_kernel<<<interBlocks, 256, 0, stream>>>(pos, iei, lw0, rw0, hL, hR, EI);
  tp_kernel<1><<<256, 512, 0, stream>>>(node, pos, iei, nullptr, nullptr, lw1, hL, ligE, EI);
  rec_kernel<<<256, 512, 0, stream>>>(node, ligE, iei, rw1, hR, outp, EI);
}

// Round 3
// 901.926 us; speedup vs baseline: 1.0012x; 1.0012x over previous
//
#include <hip/hip_runtime.h>
#include <cmath>

// ---- constants from the reference ----
constexpr float ACT_NORM = 1.6789717f;
constexpr float PW0      = 0.20412414523193154f;   // sqrt(1/24)  (== pw1/sqrt3)
constexpr float PW1      = 0.35355339059327373f;   // sqrt(3/24)
constexpr float PWREC    = 0.05590169943749474f;   // sqrt(1/320)
constexpr float INV_SQ3  = 0.57735026918962576f;

__device__ __forceinline__ float silu_n(float x) {
  return x / (1.f + __expf(-x)) * ACT_NORM;
}

// ---------------- node embedding: node[:, :16] = mlp(x), geo = 0 ----------------
__global__ __launch_bounds__(256)
void emb_kernel(const float* __restrict__ x, const float* __restrict__ w0,
                const float* __restrict__ w1, float* __restrict__ node, int N) {
  const int lane = threadIdx.x & 63;
  const int lw   = threadIdx.x >> 6;
  const int gw   = blockIdx.x * 4 + lw;
  __shared__ float sH[4][64];
  const bool valid = gw < N;
  const int n = valid ? gw : 0;
  float acc = 0.f;
#pragma unroll
  for (int a = 0; a < 10; ++a) acc = fmaf(x[n * 10 + a], w0[a * 64 + lane], acc);
  acc *= 0.31622776601683794f;   // 1/sqrt(10)
  sH[lw][lane] = silu_n(acc);
  __syncthreads();
  if (valid) {
    if (lane < 16) {
      float o = 0.f;
#pragma unroll
      for (int k = 0; k < 64; ++k) o = fmaf(sH[lw][k], w1[k * 16 + lane], o);
      node[(size_t)n * 40 + lane] = o * 0.125f;  // 1/sqrt(64)
    } else if (lane < 40) {
      node[(size_t)n * 40 + lane] = 0.f;
    }
  }
}

// ---------------- node update (per mp step) ----------------
__global__ __launch_bounds__(256)
void upd_kernel(float* __restrict__ node, const float* __restrict__ msgs,
                const float* __restrict__ w0, const float* __restrict__ w1,
                const float* __restrict__ imp, float geo_scale, float inv_sqrt_deg, int N) {
  const int lane = threadIdx.x & 63;
  const int lw   = threadIdx.x >> 6;
  const int gw   = blockIdx.x * 4 + lw;
  __shared__ float sIn[4][32];
  __shared__ float sH[4][64];
  const bool valid = gw < N;
  const int n = valid ? gw : 0;
  const float mscale = imp[0] * inv_sqrt_deg;
  if (lane < 16)      sIn[lw][lane] = msgs[(size_t)n * 40 + lane] * mscale;
  else if (lane < 32) sIn[lw][lane] = node[(size_t)n * 40 + lane - 16];
  __syncthreads();
  float acc = 0.f;
#pragma unroll
  for (int a = 0; a < 32; ++a) acc = fmaf(sIn[lw][a], w0[a * 64 + lane], acc);
  acc *= 0.17677669529663687f;   // 1/sqrt(32)
  sH[lw][lane] = silu_n(acc);
  __syncthreads();
  if (valid) {
    if (lane < 16) {
      float o = 0.f;
#pragma unroll
      for (int k = 0; k < 64; ++k) o = fmaf(sH[lw][k], w1[k * 16 + lane], o);
      node[(size_t)n * 40 + lane] = o * 0.125f;
    } else if (lane < 40) {
      const size_t gi = (size_t)n * 40 + lane;
      node[gi] = fmaf(msgs[gi], mscale, node[gi]) * geo_scale;
    }
  }
}

// ---------------- inter-edge: distance embedding -> both hidden vectors ----------------
__global__ __launch_bounds__(256)
void inter_h_kernel(const float* __restrict__ pos, const int* __restrict__ iei,
                    const float* __restrict__ lw0, const float* __restrict__ rw0,
                    float* __restrict__ hL, float* __restrict__ hR, int EI) {
  const int lane = threadIdx.x & 63;
  const int lw   = threadIdx.x >> 6;
  const int gw   = blockIdx.x * 4 + lw;
  __shared__ float sD[4][20];
  const bool valid = gw < EI;
  const int e = valid ? gw : 0;
  const int rec = iei[e], lig = iei[EI + e];
  const float dx = pos[lig * 3]     - pos[rec * 3];
  const float dy = pos[lig * 3 + 1] - pos[rec * 3 + 1];
  const float dz = pos[lig * 3 + 2] - pos[rec * 3 + 2];
  const float d = sqrtf(dx * dx + dy * dy + dz * dz);
  if (lane < 20) {
    // diff = d*(21/5) - (lane+1); demb = C * sus(diff+1)*sus(1-diff)
    const float diff = d * 4.2f - (float)(lane + 1);
    const float t1 = diff + 1.f, t2 = 1.f - diff;
    float v = 0.f;
    if (t1 > 0.f && t2 > 0.f) {
      const float C = 1.14136f * 7.3890560989306495f * 4.4721359549995794f; // 1.14136*e^2*sqrt(20)
      v = C * __expf(-1.f / t1 - 1.f / t2);
    }
    sD[lw][lane] = v;
  }
  __syncthreads();
  float a0 = 0.f, a1 = 0.f;
#pragma unroll
  for (int b = 0; b < 20; ++b) {
    const float db = sD[lw][b];
    a0 = fmaf(db, lw0[b * 64 + lane], a0);
    a1 = fmaf(db, rw0[b * 64 + lane], a1);
  }
  a0 *= 0.22360679774997896f;  // 1/sqrt(20)
  a1 *= 0.22360679774997896f;
  if (valid) {
    hL[(size_t)e * 64 + lane] = silu_n(a0);
    hR[(size_t)e * 64 + lane] = silu_n(a1);
  }
}

// ---------------- fused edge MLP (layer2) + node x sh tensor product ----------------
// MODE 0: message pass  (h from edge_attr@w0; atomicAdd into msgs[dst])
// MODE 1: lig TP        (h precomputed in hSrc; direct store to ligE[e])
template <int MODE>
__global__ __launch_bounds__(512)
void tp_kernel(const float* __restrict__ node, const float* __restrict__ pos,
               const int* __restrict__ ei, const float* __restrict__ eattr,
               const float* __restrict__ w0, const float* __restrict__ W1,
               const float* __restrict__ hSrc, float* __restrict__ out, int E) {
  __shared__ __align__(16) float sW1[64 * 576];     // 147456 B (scaled by 1/8)
  __shared__ __align__(16) float sH[8][4][64];      //   8192 B
  __shared__ float sF[8][4][48];                    //   6144 B  -> 161792 B total
  const int tid  = threadIdx.x;
  const int lane = tid & 63;
  const int wv   = tid >> 6;

  // stage W1 once per block (fits 160KB LDS); fold the 1/sqrt(64) layer scale in
  for (int i = tid * 4; i < 64 * 576; i += 512 * 4) {
    float4 v = *(const float4*)&W1[i];
    v.x *= 0.125f; v.y *= 0.125f; v.z *= 0.125f; v.w *= 0.125f;
    *(float4*)&sW1[i] = v;
  }
  __syncthreads();

  const int nB = (E + 31) >> 5;
  for (int b = blockIdx.x; b < nB; b += (int)gridDim.x) {
    const int ebase = b * 32 + wv * 4;
    float rh[4][3];
    int outn[4];
    bool val[4];
#pragma unroll
    for (int s = 0; s < 4; ++s) {
      const int e0 = ebase + s;
      val[s] = e0 < E;
      const int e = val[s] ? e0 : 0;
      const int ia = ei[e], ib = ei[E + e];
      int nsrc;
      if (MODE == 0) { nsrc = ia; outn[s] = ib; }   // src features, scatter to dst
      else           { nsrc = ib; outn[s] = e;  }   // lig features, store per edge
      const float vx = pos[ib * 3]     - pos[ia * 3];
      const float vy = pos[ib * 3 + 1] - pos[ia * 3 + 1];
      const float vz = pos[ib * 3 + 2] - pos[ia * 3 + 2];
      const float rn = rsqrtf(vx * vx + vy * vy + vz * vz);
      rh[s][0] = vx * rn; rh[s][1] = vy * rn; rh[s][2] = vz * rn;
      if (MODE == 0) {
        float acc = 0.f;
#pragma unroll
        for (int a = 0; a < 5; ++a) acc = fmaf(eattr[(size_t)e * 5 + a], w0[a * 64 + lane], acc);
        acc *= 0.4472135954999579f;   // 1/sqrt(5)
        sH[wv][s][lane] = silu_n(acc);
      } else {
        sH[wv][s][lane] = hSrc[(size_t)e * 64 + lane];
      }
      if (lane < 16) {
        sF[wv][s][lane] = node[(size_t)nsrc * 40 + lane];           // xs
      } else if (lane < 24) {
        const int u = lane - 16;
        const float x0 = node[(size_t)nsrc * 40 + 16 + u * 3];
        const float x1 = node[(size_t)nsrc * 40 + 16 + u * 3 + 1];
        const float x2 = node[(size_t)nsrc * 40 + 16 + u * 3 + 2];
        sF[wv][s][16 + u]        = x0 * rh[s][0] + x1 * rh[s][1] + x2 * rh[s][2]; // dot(xv,r^)
        sF[wv][s][24 + u * 3]     = x0;                             // xv
        sF[wv][s][24 + u * 3 + 1] = x1;
        sF[wv][s][24 + u * 3 + 2] = x2;
      }
    }
    __syncthreads();   // also fences own-wave LDS writes before reads

    // w[m] for m = lane + 64*t, t=0..8 ; w = sH(64) . sW1(64x576)
    float wacc[4][9];
#pragma unroll
    for (int s = 0; s < 4; ++s)
#pragma unroll
      for (int t = 0; t < 9; ++t) wacc[s][t] = 0.f;

    for (int k4 = 0; k4 < 64; k4 += 4) {
      float4 h4[4];
#pragma unroll
      for (int s = 0; s < 4; ++s) h4[s] = *(const float4*)&sH[wv][s][k4];
#pragma unroll
      for (int kk = 0; kk < 4; ++kk) {
        float w1v[9];
        const float* rowp = &sW1[(k4 + kk) * 576 + lane];
#pragma unroll
        for (int t = 0; t < 9; ++t) w1v[t] = rowp[64 * t];
#pragma unroll
        for (int s = 0; s < 4; ++s) {
          const float hv = (&h4[s].x)[kk];
#pragma unroll
          for (int t = 0; t < 9; ++t) wacc[s][t] = fmaf(hv, w1v[t], wacc[s][t]);
        }
      }
    }

    // TP epilogue. Slots t=0..5 are scalar-path (m<384, out col = lane&15, U=(lane>>4)+4t),
    // slots 6..8 are vector-path (out col = lane&7, U=(lane>>3)+8(t-6)).
    const int ub  = lane >> 4;
    const int ub2 = lane >> 3;
#pragma unroll
    for (int s = 0; s < 4; ++s) {
      float cs = 0.f;
#pragma unroll
      for (int t = 0; t < 6; ++t)
        cs = fmaf(PW0 * sF[wv][s][ub + 4 * t], wacc[s][t], cs);   // sF[U]: xs (U<16) / dotp (U>=16)
      cs += __shfl_xor(cs, 16);
      cs += __shfl_xor(cs, 32);

      const float xsA = sF[wv][s][ub2];        // t=6: U=ub2     (<16) -> xs path
      const float xsB = sF[wv][s][ub2 + 8];    // t=7: U=ub2+8   (<16) -> xs path
      const float sxw = PW1 * (xsA * wacc[s][6] + xsB * wacc[s][7]);
      float cv0 = fmaf(PW0 * sF[wv][s][24 + ub2 * 3],     wacc[s][8], sxw * rh[s][0]); // t=8: xv path
      float cv1 = fmaf(PW0 * sF[wv][s][24 + ub2 * 3 + 1], wacc[s][8], sxw * rh[s][1]);
      float cv2 = fmaf(PW0 * sF[wv][s][24 + ub2 * 3 + 2], wacc[s][8], sxw * rh[s][2]);
      cv0 += __shfl_xor(cv0, 8); cv0 += __shfl_xor(cv0, 16); cv0 += __shfl_xor(cv0, 32);
      cv1 += __shfl_xor(cv1, 8); cv1 += __shfl_xor(cv1, 16); cv1 += __shfl_xor(cv1, 32);
      cv2 += __shfl_xor(cv2, 8); cv2 += __shfl_xor(cv2, 16); cv2 += __shfl_xor(cv2, 32);

      if (val[s]) {
        const size_t ob = (size_t)outn[s] * 40;
        if (MODE == 0) {
          if (lane < 16) atomicAdd(&out[ob + lane], cs);
          if (lane < 8) {
            atomicAdd(&out[ob + 16 + lane * 3],     cv0);
            atomicAdd(&out[ob + 16 + lane * 3 + 1], cv1);
            atomicAdd(&out[ob + 16 + lane * 3 + 2], cv2);
          }
        } else {
          if (lane < 16) out[ob + lane] = cs;
          if (lane < 8) {
            out[ob + 16 + lane * 3]     = cv0;
            out[ob + 16 + lane * 3 + 1] = cv1;
            out[ob + 16 + lane * 3 + 2] = cv2;
          }
        }
      }
    }
  }
}

// ---------------- rec MLP (layer2, 64x2560) + node x node -> 8x0e TP ----------------
__global__ __launch_bounds__(512)
void rec_kernel(const float* __restrict__ node, const float* __restrict__ ligE,
                const int* __restrict__ iei, const float* __restrict__ RW1,
                const float* __restrict__ hR, float* __restrict__ out, int EI) {
  __shared__ __align__(16) float sW1[64 * 512];    // 131072 B (one N-chunk, scaled 1/8)
  __shared__ __align__(16) float sH[8][4][64];     //   8192 B
  __shared__ float sF[8][4][80];                   //  10240 B -> 149504 B total
  const int tid  = threadIdx.x;
  const int lane = tid & 63;
  const int wv   = tid >> 6;
  const int nB = (EI + 31) >> 5;
  for (int b = blockIdx.x; b < nB; b += (int)gridDim.x) {
    const int ebase = b * 32 + wv * 4;
    bool val[4]; int eidx[4];
#pragma unroll
    for (int s = 0; s < 4; ++s) {
      const int e0 = ebase + s;
      val[s] = e0 < EI;
      const int e = val[s] ? e0 : 0;
      eidx[s] = e;
      const int rec = iei[e];
      sH[wv][s][lane] = hR[(size_t)e * 64 + lane];
      if (lane < 40) {
        sF[wv][s][lane]      = ligE[(size_t)e * 40 + lane];        // xs_l[0:16], xv_l[16:40]
        sF[wv][s][40 + lane] = node[(size_t)rec * 40 + lane];      // ys_r[40:56], yv_r[56:80]
      }
    }
    float oacc[4] = {0.f, 0.f, 0.f, 0.f};
#pragma unroll 1
    for (int nc = 0; nc < 5; ++nc) {
      __syncthreads();
      for (int i = tid * 4; i < 64 * 512; i += 512 * 4) {
        const int k = i >> 9, c = i & 511;
        float4 v = *(const float4*)&RW1[(size_t)k * 2560 + nc * 512 + c];
        v.x *= 0.125f; v.y *= 0.125f; v.z *= 0.125f; v.w *= 0.125f;
        *(float4*)&sW1[i] = v;
      }
      __syncthreads();

      float wacc[4][8];
#pragma unroll
      for (int s = 0; s < 4; ++s)
#pragma unroll
        for (int t = 0; t < 8; ++t) wacc[s][t] = 0.f;

      for (int k4 = 0; k4 < 64; k4 += 4) {
        float4 h4[4];
#pragma unroll
        for (int s = 0; s < 4; ++s) h4[s] = *(const float4*)&sH[wv][s][k4];
#pragma unroll
        for (int kk = 0; kk < 4; ++kk) {
          float w1v[8];
          const float* rowp = &sW1[(k4 + kk) * 512 + lane];
#pragma unroll
          for (int t = 0; t < 8; ++t) w1v[t] = rowp[64 * t];
#pragma unroll
          for (int s = 0; s < 4; ++s) {
            const float hv = (&h4[s].x)[kk];
#pragma unroll
            for (int t = 0; t < 8; ++t) wacc[s][t] = fmaf(hv, w1v[t], wacc[s][t]);
          }
        }
      }

      // epilogue: m = nc*512 + lane + 64t ; out col = lane&7 (uniform per lane)
      const int l3 = lane >> 3;
      if (nc < 4) {           // scalar path: uv = m>>3 in [0,256)
#pragma unroll
        for (int s = 0; s < 4; ++s) {
          float o = 0.f;
#pragma unroll
          for (int t = 0; t < 8; ++t) {
            const int uv = nc * 64 + 8 * t + l3;
            const int u = uv >> 4, v = uv & 15;
            o = fmaf(sF[wv][s][u] * sF[wv][s][40 + v], wacc[s][t], o);
          }
          oacc[s] += o;
        }
      } else {                // vector path: uv2 = (m-2048)>>3 -> u=t, v=l3
#pragma unroll
        for (int s = 0; s < 4; ++s) {
          float o = 0.f;
#pragma unroll
          for (int t = 0; t < 8; ++t) {
            const float dp = sF[wv][s][16 + t * 3]     * sF[wv][s][56 + l3 * 3]
                           + sF[wv][s][16 + t * 3 + 1] * sF[wv][s][56 + l3 * 3 + 1]
                           + sF[wv][s][16 + t * 3 + 2] * sF[wv][s][56 + l3 * 3 + 2];
            o = fmaf(dp * INV_SQ3, wacc[s][t], o);
          }
          oacc[s] += o;
        }
      }
    }
#pragma unroll
    for (int s = 0; s < 4; ++s) {
      float v = oacc[s];
      v += __shfl_xor(v, 8); v += __shfl_xor(v, 16); v += __shfl_xor(v, 32);
      if (val[s] && lane < 8) out[(size_t)eidx[s] * 8 + lane] = v * PWREC;
    }
  }
}

extern "C" void kernel_launch(void* const* d_in, const int* in_sizes, int n_in,
                              void* d_out, int out_size, void* d_ws, size_t ws_size,
                              hipStream_t stream) {
  (void)n_in; (void)out_size; (void)ws_size;
  const float* x      = (const float*)d_in[0];
  const float* pos    = (const float*)d_in[1];
  const int*   ei     = (const int*)  d_in[2];
  const float* eattr  = (const float*)d_in[3];
  const int*   iei    = (const int*)  d_in[4];
  const float* emb_w0 = (const float*)d_in[5];
  const float* emb_w1 = (const float*)d_in[6];
  const float* imp0   = (const float*)d_in[7];
  const float* m0w0   = (const float*)d_in[8];
  const float* m0w1   = (const float*)d_in[9];
  const float* u0w0   = (const float*)d_in[10];
  const float* u0w1   = (const float*)d_in[11];
  const float* imp1   = (const float*)d_in[12];
  const float* m1w0   = (const float*)d_in[13];
  const float* m1w1   = (const float*)d_in[14];
  const float* u1w0   = (const float*)d_in[15];
  const float* u1w1   = (const float*)d_in[16];
  const float* lw0    = (const float*)d_in[17];
  const float* lw1    = (const float*)d_in[18];
  const float* rw0    = (const float*)d_in[19];
  const float* rw1    = (const float*)d_in[20];

  const int N  = in_sizes[1] / 3;
  const int E  = in_sizes[2] / 2;
  const int EI = in_sizes[4] / 2;

  float* node = (float*)d_ws;
  float* msgs = node + (size_t)N * 40;
  float* hL   = msgs + (size_t)N * 40;
  float* hR   = hL + (size_t)EI * 64;
  float* ligE = hR + (size_t)EI * 64;
  float* outp = (float*)d_out;

  const float inv_sqrt_deg = 1.0f / sqrtf((float)E / (float)N);

  const int nodeBlocks = (N + 3) / 4;
  const int interBlocks = (EI + 3) / 4;

  emb_kernel<<<nodeBlocks, 256, 0, stream>>>(x, emb_w0, emb_w1, node, N);

  // message pass 0
  hipMemsetAsync(msgs, 0, (size_t)N * 40 * sizeof(float), stream);
  tp_kernel<0><<<256, 512, 0, stream>>>(node, pos, ei, eattr, m0w0, m0w1, nullptr, msgs, E);
  upd_kernel<<<nodeBlocks, 256, 0, stream>>>(node, msgs, u0w0, u0w1, imp0, 1.0f, inv_sqrt_deg, N);

  // message pass 1
  hipMemsetAsync(msgs, 0, (size_t)N * 40 * sizeof(float), stream);
  tp_kernel<0><<<256, 512, 0, stream>>>(node, pos, ei, eattr, m1w0, m1w1, nullptr, msgs, E);
  upd_kernel<<<nodeBlocks, 256, 0, stream>>>(node, msgs, u1w0, u1w1, imp1, 0.5f, inv_sqrt_deg, N);

  // inter edges
  inter_h_kernel<<<interBlocks, 256, 0, stream>>>(pos, iei, lw0, rw0, hL, hR, EI);
  tp_kernel<1><<<256, 512, 0, stream>>>(node, pos, iei, nullptr, nullptr, lw1, hL, ligE, EI);
  rec_kernel<<<256, 512, 0, stream>>>(node, ligE, iei, rw1, hR, outp, EI);
}

// Round 4
// 864.656 us; speedup vs baseline: 1.0444x; 1.0431x over previous
//
#include <hip/hip_runtime.h>
#include <cmath>

// ---- constants from the reference ----
constexpr float ACT_NORM = 1.6789717f;
constexpr float PW0      = 0.20412414523193154f;   // sqrt(1/24)  (== pw1/sqrt3)
constexpr float PW0C     = 0.20412414523193154f * 0.125f; // PW0 * layer-scale for unscaled wc slot
constexpr float PW1      = 0.35355339059327373f;   // sqrt(3/24)
constexpr float PWREC    = 0.05590169943749474f;   // sqrt(1/320)
constexpr float INV_SQ3  = 0.57735026918962576f;

__device__ __forceinline__ float silu_n(float x) {
  return x / (1.f + __expf(-x)) * ACT_NORM;
}

// ---------------- node embedding: node[:, :16] = mlp(x), geo = 0 ----------------
__global__ __launch_bounds__(256)
void emb_kernel(const float* __restrict__ x, const float* __restrict__ w0,
                const float* __restrict__ w1, float* __restrict__ node, int N) {
  const int lane = threadIdx.x & 63;
  const int lw   = threadIdx.x >> 6;
  const int gw   = blockIdx.x * 4 + lw;
  __shared__ float sH[4][64];
  const bool valid = gw < N;
  const int n = valid ? gw : 0;
  float acc = 0.f;
#pragma unroll
  for (int a = 0; a < 10; ++a) acc = fmaf(x[n * 10 + a], w0[a * 64 + lane], acc);
  acc *= 0.31622776601683794f;   // 1/sqrt(10)
  sH[lw][lane] = silu_n(acc);
  __syncthreads();
  if (valid) {
    if (lane < 16) {
      float o = 0.f;
#pragma unroll
      for (int k = 0; k < 64; ++k) o = fmaf(sH[lw][k], w1[k * 16 + lane], o);
      node[(size_t)n * 40 + lane] = o * 0.125f;  // 1/sqrt(64)
    } else if (lane < 40) {
      node[(size_t)n * 40 + lane] = 0.f;
    }
  }
}

// ---------------- node update (per mp step) ----------------
__global__ __launch_bounds__(256)
void upd_kernel(float* __restrict__ node, const float* __restrict__ msgs,
                const float* __restrict__ w0, const float* __restrict__ w1,
                const float* __restrict__ imp, float geo_scale, float inv_sqrt_deg, int N) {
  const int lane = threadIdx.x & 63;
  const int lw   = threadIdx.x >> 6;
  const int gw   = blockIdx.x * 4 + lw;
  __shared__ float sIn[4][32];
  __shared__ float sH[4][64];
  const bool valid = gw < N;
  const int n = valid ? gw : 0;
  const float mscale = imp[0] * inv_sqrt_deg;
  if (lane < 16)      sIn[lw][lane] = msgs[(size_t)n * 40 + lane] * mscale;
  else if (lane < 32) sIn[lw][lane] = node[(size_t)n * 40 + lane - 16];
  __syncthreads();
  float acc = 0.f;
#pragma unroll
  for (int a = 0; a < 32; ++a) acc = fmaf(sIn[lw][a], w0[a * 64 + lane], acc);
  acc *= 0.17677669529663687f;   // 1/sqrt(32)
  sH[lw][lane] = silu_n(acc);
  __syncthreads();
  if (valid) {
    if (lane < 16) {
      float o = 0.f;
#pragma unroll
      for (int k = 0; k < 64; ++k) o = fmaf(sH[lw][k], w1[k * 16 + lane], o);
      node[(size_t)n * 40 + lane] = o * 0.125f;
    } else if (lane < 40) {
      const size_t gi = (size_t)n * 40 + lane;
      node[gi] = fmaf(msgs[gi], mscale, node[gi]) * geo_scale;
    }
  }
}

// ---------------- inter-edge: distance embedding -> both hidden vectors ----------------
__global__ __launch_bounds__(256)
void inter_h_kernel(const float* __restrict__ pos, const int* __restrict__ iei,
                    const float* __restrict__ lw0, const float* __restrict__ rw0,
                    float* __restrict__ hL, float* __restrict__ hR, int EI) {
  const int lane = threadIdx.x & 63;
  const int lw   = threadIdx.x >> 6;
  const int gw   = blockIdx.x * 4 + lw;
  __shared__ float sD[4][20];
  const bool valid = gw < EI;
  const int e = valid ? gw : 0;
  const int rec = iei[e], lig = iei[EI + e];
  const float dx = pos[lig * 3]     - pos[rec * 3];
  const float dy = pos[lig * 3 + 1] - pos[rec * 3 + 1];
  const float dz = pos[lig * 3 + 2] - pos[rec * 3 + 2];
  const float d = sqrtf(dx * dx + dy * dy + dz * dz);
  if (lane < 20) {
    const float diff = d * 4.2f - (float)(lane + 1);
    const float t1 = diff + 1.f, t2 = 1.f - diff;
    float v = 0.f;
    if (t1 > 0.f && t2 > 0.f) {
      const float C = 1.14136f * 7.3890560989306495f * 4.4721359549995794f; // 1.14136*e^2*sqrt(20)
      v = C * __expf(-1.f / t1 - 1.f / t2);
    }
    sD[lw][lane] = v;
  }
  __syncthreads();
  float a0 = 0.f, a1 = 0.f;
#pragma unroll
  for (int b = 0; b < 20; ++b) {
    const float db = sD[lw][b];
    a0 = fmaf(db, lw0[b * 64 + lane], a0);
    a1 = fmaf(db, rw0[b * 64 + lane], a1);
  }
  a0 *= 0.22360679774997896f;  // 1/sqrt(20)
  a1 *= 0.22360679774997896f;
  if (valid) {
    hL[(size_t)e * 64 + lane] = silu_n(a0);
    hR[(size_t)e * 64 + lane] = silu_n(a1);
  }
}

// ---------------- fused edge MLP (layer2) + node x sh tensor product ----------------
// Weight layout in LDS: sA[k][lane][t0..3], sB[k][lane][t4..7] (wide conflict-free reads);
// slot t=8 is read from global (L2-hot), double-buffered in registers.
// S = 8 edges per wave. MODE 0: msg pass (atomicAdd into msgs[dst]); MODE 1: lig TP (store).
template <int MODE>
__global__ __launch_bounds__(512, 2)
void tp_kernel(const float* __restrict__ node, const float* __restrict__ pos,
               const int* __restrict__ ei, const float* __restrict__ eattr,
               const float* __restrict__ w0, const float* __restrict__ W1,
               const float* __restrict__ hSrc, float* __restrict__ out, int E) {
  __shared__ __align__(16) float sA[64 * 64 * 4];   // 65536 B  t=0..3, scaled 1/8
  __shared__ __align__(16) float sB[64 * 64 * 4];   // 65536 B  t=4..7, scaled 1/8
  __shared__ __align__(16) float sH[8][8][64];      // 16384 B
  __shared__ float sF[8][8][52];                    // 13312 B  -> 160768 B total
  const int tid  = threadIdx.x;
  const int lane = tid & 63;
  const int wv   = tid >> 6;

  // stage A,B once per block (transform [k][m] -> [k][lane][t]); coalesced global reads
  for (int j = tid; j < 4096; j += 512) {
    const int k = j >> 6, l = j & 63;
    const float* src = &W1[k * 576 + l];
    float4 va, vb;
    va.x = src[0]   * 0.125f; va.y = src[64]  * 0.125f;
    va.z = src[128] * 0.125f; va.w = src[192] * 0.125f;
    vb.x = src[256] * 0.125f; vb.y = src[320] * 0.125f;
    vb.z = src[384] * 0.125f; vb.w = src[448] * 0.125f;
    *(float4*)&sA[j * 4] = va;
    *(float4*)&sB[j * 4] = vb;
  }
  __syncthreads();

  float w0r[5];
  if (MODE == 0) {
#pragma unroll
    for (int a = 0; a < 5; ++a) w0r[a] = w0[a * 64 + lane] * 0.4472135954999579f; // fold 1/sqrt(5)
  }
  const float* Wc = W1 + 512;   // t=8 column, unscaled (1/8 folded into PW0C)

  const int nB = (E + 63) >> 6;
  for (int b = blockIdx.x; b < nB; b += (int)gridDim.x) {
    const int ebase = b * 64 + wv * 8;
    int outn[8];
    bool val[8];
#pragma unroll
    for (int s = 0; s < 8; ++s) {
      const int e0 = ebase + s;
      val[s] = e0 < E;
      const int e = val[s] ? e0 : 0;
      const int ia = ei[e], ib = ei[E + e];
      int nsrc;
      if (MODE == 0) { nsrc = ia; outn[s] = ib; }   // src features, scatter to dst
      else           { nsrc = ib; outn[s] = e;  }   // lig features, store per edge
      const float vx = pos[ib * 3]     - pos[ia * 3];
      const float vy = pos[ib * 3 + 1] - pos[ia * 3 + 1];
      const float vz = pos[ib * 3 + 2] - pos[ia * 3 + 2];
      const float rn = rsqrtf(vx * vx + vy * vy + vz * vz);
      const float rx = vx * rn, ry = vy * rn, rz = vz * rn;
      if (MODE == 0) {
        float acc = 0.f;
#pragma unroll
        for (int a = 0; a < 5; ++a) acc = fmaf(eattr[(size_t)e * 5 + a], w0r[a], acc);
        sH[wv][s][lane] = silu_n(acc);
      } else {
        sH[wv][s][lane] = hSrc[(size_t)e * 64 + lane];
      }
      if (lane < 16) {
        sF[wv][s][lane] = node[(size_t)nsrc * 40 + lane];           // xs
      } else if (lane < 24) {
        const int u = lane - 16;
        const float x0 = node[(size_t)nsrc * 40 + 16 + u * 3];
        const float x1 = node[(size_t)nsrc * 40 + 16 + u * 3 + 1];
        const float x2 = node[(size_t)nsrc * 40 + 16 + u * 3 + 2];
        sF[wv][s][16 + u]         = x0 * rx + x1 * ry + x2 * rz;    // dot(xv, r^)
        sF[wv][s][24 + u * 3]     = x0;                             // xv
        sF[wv][s][24 + u * 3 + 1] = x1;
        sF[wv][s][24 + u * 3 + 2] = x2;
      } else if (lane < 27) {
        sF[wv][s][48 + (lane - 24)] = (lane == 24) ? rx : ((lane == 25) ? ry : rz);
      }
    }
    // no barrier needed: sH/sF slices are per-wave private (compiler handles same-wave LDS RAW)

    // w[m] for m = lane + 64*t, t=0..8 ; w = h(64) . W1(64x576)
    float wacc[8][9];
#pragma unroll
    for (int s = 0; s < 8; ++s)
#pragma unroll
      for (int t = 0; t < 9; ++t) wacc[s][t] = 0.f;

    float wcur[4], wnxt[4];
#pragma unroll
    for (int kk = 0; kk < 4; ++kk) wcur[kk] = Wc[kk * 576 + lane];

    for (int k4 = 0; k4 < 64; k4 += 4) {
      if (k4 < 60) {
#pragma unroll
        for (int kk = 0; kk < 4; ++kk) wnxt[kk] = Wc[(size_t)(k4 + 4 + kk) * 576 + lane];
      }
      float4 h4[8];
#pragma unroll
      for (int s = 0; s < 8; ++s) h4[s] = *(const float4*)&sH[wv][s][k4];
#pragma unroll
      for (int kk = 0; kk < 4; ++kk) {
        const int k = k4 + kk;
        const float4 wa = *(const float4*)&sA[(k * 64 + lane) * 4];
        const float4 wb = *(const float4*)&sB[(k * 64 + lane) * 4];
        const float  wc = wcur[kk];
#pragma unroll
        for (int s = 0; s < 8; ++s) {
          const float hv = (&h4[s].x)[kk];
          wacc[s][0] = fmaf(hv, wa.x, wacc[s][0]);
          wacc[s][1] = fmaf(hv, wa.y, wacc[s][1]);
          wacc[s][2] = fmaf(hv, wa.z, wacc[s][2]);
          wacc[s][3] = fmaf(hv, wa.w, wacc[s][3]);
          wacc[s][4] = fmaf(hv, wb.x, wacc[s][4]);
          wacc[s][5] = fmaf(hv, wb.y, wacc[s][5]);
          wacc[s][6] = fmaf(hv, wb.z, wacc[s][6]);
          wacc[s][7] = fmaf(hv, wb.w, wacc[s][7]);
          wacc[s][8] = fmaf(hv, wc,   wacc[s][8]);
        }
      }
      if (k4 < 60) {
#pragma unroll
        for (int kk = 0; kk < 4; ++kk) wcur[kk] = wnxt[kk];
      }
    }

    // TP epilogue. t=0..5 scalar-path (out col = lane&15, U=(lane>>4)+4t),
    // t=6..8 vector-path (out col = lane&7, U=(lane>>3)+8(t-6)).
    const int ub  = lane >> 4;
    const int ub2 = lane >> 3;
#pragma unroll
    for (int s = 0; s < 8; ++s) {
      float cs = 0.f;
#pragma unroll
      for (int t = 0; t < 6; ++t)
        cs = fmaf(PW0 * sF[wv][s][ub + 4 * t], wacc[s][t], cs);
      cs += __shfl_xor(cs, 16);
      cs += __shfl_xor(cs, 32);

      const float rx = sF[wv][s][48], ry = sF[wv][s][49], rz = sF[wv][s][50];
      const float sxw = PW1 * (sF[wv][s][ub2] * wacc[s][6] + sF[wv][s][ub2 + 8] * wacc[s][7]);
      float cv0 = fmaf(PW0C * sF[wv][s][24 + ub2 * 3],     wacc[s][8], sxw * rx);
      float cv1 = fmaf(PW0C * sF[wv][s][24 + ub2 * 3 + 1], wacc[s][8], sxw * ry);
      float cv2 = fmaf(PW0C * sF[wv][s][24 + ub2 * 3 + 2], wacc[s][8], sxw * rz);
      cv0 += __shfl_xor(cv0, 8); cv0 += __shfl_xor(cv0, 16); cv0 += __shfl_xor(cv0, 32);
      cv1 += __shfl_xor(cv1, 8); cv1 += __shfl_xor(cv1, 16); cv1 += __shfl_xor(cv1, 32);
      cv2 += __shfl_xor(cv2, 8); cv2 += __shfl_xor(cv2, 16); cv2 += __shfl_xor(cv2, 32);

      if (val[s]) {
        const size_t ob = (size_t)outn[s] * 40;
        if (MODE == 0) {
          if (lane < 16) atomicAdd(&out[ob + lane], cs);
          if (lane < 8) {
            atomicAdd(&out[ob + 16 + lane * 3],     cv0);
            atomicAdd(&out[ob + 16 + lane * 3 + 1], cv1);
            atomicAdd(&out[ob + 16 + lane * 3 + 2], cv2);
          }
        } else {
          if (lane < 16) out[ob + lane] = cs;
          if (lane < 8) {
            out[ob + 16 + lane * 3]     = cv0;
            out[ob + 16 + lane * 3 + 1] = cv1;
            out[ob + 16 + lane * 3 + 2] = cv2;
          }
        }
      }
    }
  }
}

// ---------------- rec MLP (layer2, 64x2560) + node x node -> 8x0e TP ----------------
// 20 chunks of 128 cols; chunk layout sA[k][lane][t0..1]; S=8 edges/wave; 2 blocks/CU.
__global__ __launch_bounds__(512, 4)
void rec_kernel(const float* __restrict__ node, const float* __restrict__ ligE,
                const int* __restrict__ iei, const float* __restrict__ RW1,
                const float* __restrict__ hR, float* __restrict__ out, int EI) {
  __shared__ __align__(16) float sA[64 * 64 * 2];   // 32768 B (scaled 1/8)
  __shared__ __align__(16) float sH[8][8][64];      // 16384 B
  __shared__ float sF[8][8][80];                    // 20480 B -> 69632 B total
  const int tid  = threadIdx.x;
  const int lane = tid & 63;
  const int wv   = tid >> 6;
  const int nB = (EI + 63) >> 6;
  for (int b = blockIdx.x; b < nB; b += (int)gridDim.x) {
    const int ebase = b * 64 + wv * 8;
    bool val[8]; int eidx[8];
#pragma unroll
    for (int s = 0; s < 8; ++s) {
      const int e0 = ebase + s;
      val[s] = e0 < EI;
      const int e = val[s] ? e0 : 0;
      eidx[s] = e;
      const int rec = iei[e];
      sH[wv][s][lane] = hR[(size_t)e * 64 + lane];
      if (lane < 40) {
        sF[wv][s][lane]      = ligE[(size_t)e * 40 + lane];        // xs_l[0:16], xv_l[16:40]
        sF[wv][s][40 + lane] = node[(size_t)rec * 40 + lane];      // ys_r[40:56], yv_r[56:80]
      }
    }
    float oacc[8];
#pragma unroll
    for (int s = 0; s < 8; ++s) oacc[s] = 0.f;

#pragma unroll 1
    for (int nc = 0; nc < 20; ++nc) {
      __syncthreads();
      for (int j = tid; j < 4096; j += 512) {
        const int k = j >> 6, l = j & 63;
        const float* src = &RW1[(size_t)k * 2560 + nc * 128 + l];
        float2 v; v.x = src[0] * 0.125f; v.y = src[64] * 0.125f;
        *(float2*)&sA[j * 2] = v;
      }
      __syncthreads();

      float wacc[8][2];
#pragma unroll
      for (int s = 0; s < 8; ++s) { wacc[s][0] = 0.f; wacc[s][1] = 0.f; }

      for (int k4 = 0; k4 < 64; k4 += 4) {
        float4 h4[8];
#pragma unroll
        for (int s = 0; s < 8; ++s) h4[s] = *(const float4*)&sH[wv][s][k4];
#pragma unroll
        for (int kk = 0; kk < 4; ++kk) {
          const float2 w2 = *(const float2*)&sA[((k4 + kk) * 64 + lane) * 2];
#pragma unroll
          for (int s = 0; s < 8; ++s) {
            const float hv = (&h4[s].x)[kk];
            wacc[s][0] = fmaf(hv, w2.x, wacc[s][0]);
            wacc[s][1] = fmaf(hv, w2.y, wacc[s][1]);
          }
        }
      }

      // epilogue: m = nc*128 + t*64 + lane ; col = lane&7 ; uv = m>>3 = nc*16 + t*8 + l3
      const int l3 = lane >> 3;
#pragma unroll
      for (int t = 0; t < 2; ++t) {
        const int uvbase = nc * 16 + t * 8;
        if (uvbase < 256) {        // scalar path (wave-uniform branch)
          const int uv = uvbase + l3;
          const int u = uv >> 4, v = uv & 15;
#pragma unroll
          for (int s = 0; s < 8; ++s)
            oacc[s] = fmaf(sF[wv][s][u] * sF[wv][s][40 + v], wacc[s][t], oacc[s]);
        } else {                   // vector path
          const int uv2 = uvbase - 256 + l3;
          const int u = uv2 >> 3, v = uv2 & 7;
#pragma unroll
          for (int s = 0; s < 8; ++s) {
            const float dp = sF[wv][s][16 + u * 3]     * sF[wv][s][56 + v * 3]
                           + sF[wv][s][16 + u * 3 + 1] * sF[wv][s][56 + v * 3 + 1]
                           + sF[wv][s][16 + u * 3 + 2] * sF[wv][s][56 + v * 3 + 2];
            oacc[s] = fmaf(dp * INV_SQ3, wacc[s][t], oacc[s]);
          }
        }
      }
    }
#pragma unroll
    for (int s = 0; s < 8; ++s) {
      float v = oacc[s];
      v += __shfl_xor(v, 8); v += __shfl_xor(v, 16); v += __shfl_xor(v, 32);
      if (val[s] && lane < 8) out[(size_t)eidx[s] * 8 + lane] = v * PWREC;
    }
  }
}

extern "C" void kernel_launch(void* const* d_in, const int* in_sizes, int n_in,
                              void* d_out, int out_size, void* d_ws, size_t ws_size,
                              hipStream_t stream) {
  (void)n_in; (void)out_size; (void)ws_size;
  const float* x      = (const float*)d_in[0];
  const float* pos    = (const float*)d_in[1];
  const int*   ei     = (const int*)  d_in[2];
  const float* eattr  = (const float*)d_in[3];
  const int*   iei    = (const int*)  d_in[4];
  const float* emb_w0 = (const float*)d_in[5];
  const float* emb_w1 = (const float*)d_in[6];
  const float* imp0   = (const float*)d_in[7];
  const float* m0w0   = (const float*)d_in[8];
  const float* m0w1   = (const float*)d_in[9];
  const float* u0w0   = (const float*)d_in[10];
  const float* u0w1   = (const float*)d_in[11];
  const float* imp1   = (const float*)d_in[12];
  const float* m1w0   = (const float*)d_in[13];
  const float* m1w1   = (const float*)d_in[14];
  const float* u1w0   = (const float*)d_in[15];
  const float* u1w1   = (const float*)d_in[16];
  const float* lw0    = (const float*)d_in[17];
  const float* lw1    = (const float*)d_in[18];
  const float* rw0    = (const float*)d_in[19];
  const float* rw1    = (const float*)d_in[20];

  const int N  = in_sizes[1] / 3;
  const int E  = in_sizes[2] / 2;
  const int EI = in_sizes[4] / 2;

  float* node = (float*)d_ws;
  float* msgs = node + (size_t)N * 40;
  float* hL   = msgs + (size_t)N * 40;
  float* hR   = hL + (size_t)EI * 64;
  float* ligE = hR + (size_t)EI * 64;
  float* outp = (float*)d_out;

  const float inv_sqrt_deg = 1.0f / sqrtf((float)E / (float)N);

  const int nodeBlocks = (N + 3) / 4;
  const int interBlocks = (EI + 3) / 4;

  emb_kernel<<<nodeBlocks, 256, 0, stream>>>(x, emb_w0, emb_w1, node, N);

  // message pass 0
  hipMemsetAsync(msgs, 0, (size_t)N * 40 * sizeof(float), stream);
  tp_kernel<0><<<256, 512, 0, stream>>>(node, pos, ei, eattr, m0w0, m0w1, nullptr, msgs, E);
  upd_kernel<<<nodeBlocks, 256, 0, stream>>>(node, msgs, u0w0, u0w1, imp0, 1.0f, inv_sqrt_deg, N);

  // message pass 1
  hipMemsetAsync(msgs, 0, (size_t)N * 40 * sizeof(float), stream);
  tp_kernel<0><<<256, 512, 0, stream>>>(node, pos, ei, eattr, m1w0, m1w1, nullptr, msgs, E);
  upd_kernel<<<nodeBlocks, 256, 0, stream>>>(node, msgs, u1w0, u1w1, imp1, 0.5f, inv_sqrt_deg, N);

  // inter edges
  inter_h_kernel<<<interBlocks, 256, 0, stream>>>(pos, iei, lw0, rw0, hL, hR, EI);
  tp_kernel<1><<<256, 512, 0, stream>>>(node, pos, iei, nullptr, nullptr, lw1, hL, ligE, EI);
  rec_kernel<<<512, 512, 0, stream>>>(node, ligE, iei, rw1, hR, outp, EI);
}